// Round 5
// baseline (503.412 us; speedup 1.0000x reference)
//
#include <hip/hip_runtime.h>
#include <math.h>

#define F_IN 500
#define HID 32
#define NCLS 40

// CSR radix build: bucket = 256 consecutive dst nodes. Requires N <= 131072
// (src packs in 17 bits, local dst in 9 -> one int per staged edge).
#define NPB 256
#define MAXB 512
#define EPB 16384

// ---------------- phase 1a: per-bucket edge counts (LDS-aggregated) ----------------
__global__ __launch_bounds__(256) void csr_count_kernel(const int* __restrict__ dst, int E,
                                                        int* __restrict__ gcnt, int nb) {
    __shared__ int cnt[MAXB];
    int tid = threadIdx.x;
    for (int i = tid; i < MAXB; i += 256) cnt[i] = 0;
    __syncthreads();
    long e0 = (long)blockIdx.x * EPB;
    #pragma unroll 4
    for (int k = 0; k < EPB / 256; ++k) {
        long e = e0 + tid + k * 256;
        if (e < E) atomicAdd(&cnt[dst[e] >> 8], 1);
    }
    __syncthreads();
    for (int b = tid; b < nb; b += 256)
        if (cnt[b]) atomicAdd(&gcnt[b], cnt[b]);
}

// ---------------- phase 1b: exclusive scan of bucket counts (1 block) ----------------
__global__ __launch_bounds__(512) void csr_bscan_kernel(const int* __restrict__ gcnt,
                                                        int* __restrict__ bucketptr,
                                                        int* __restrict__ bcur, int nb) {
    __shared__ int wsum[8];
    int tid = threadIdx.x, lane = tid & 63, wid = tid >> 6;
    int v = (tid < nb) ? gcnt[tid] : 0;
    int x = v;
    #pragma unroll
    for (int off = 1; off < 64; off <<= 1) {
        int y = __shfl_up(x, off);
        if (lane >= off) x += y;
    }
    if (lane == 63) wsum[wid] = x;
    __syncthreads();
    if (wid == 0 && lane < 8) {
        int wv = wsum[lane];
        #pragma unroll
        for (int off = 1; off < 8; off <<= 1) {
            int y = __shfl_up(wv, off);
            if (lane >= off) wv += y;
        }
        wsum[lane] = wv;
    }
    __syncthreads();
    int excl = ((wid > 0) ? wsum[wid - 1] : 0) + x - v;
    if (tid < nb) { bucketptr[tid] = excl; bcur[tid] = excl; }
    if (tid == nb - 1) bucketptr[nb] = excl + v;
}

// ---------------- phase 1c: LDS-bin edges by bucket, write staged runs ----------------
__global__ __launch_bounds__(512) void csr_bin_kernel(const int* __restrict__ src,
                                                      const int* __restrict__ dst, int E,
                                                      int* __restrict__ bcur,
                                                      int* __restrict__ gstage, int nb) {
    __shared__ int cnt[MAXB], off[MAXB], cur[MAXB], gbase[MAXB];
    __shared__ int stage[EPB];
    __shared__ int wsum[8];
    int tid = threadIdx.x, lane = tid & 63, wid = tid >> 6;
    cnt[tid] = 0;
    __syncthreads();
    long e0 = (long)blockIdx.x * EPB;
    #pragma unroll 4
    for (int k = 0; k < EPB / 512; ++k) {
        long e = e0 + tid + k * 512;
        if (e < E) atomicAdd(&cnt[dst[e] >> 8], 1);
    }
    __syncthreads();
    int v = cnt[tid];
    int x = v;
    #pragma unroll
    for (int o = 1; o < 64; o <<= 1) {
        int y = __shfl_up(x, o);
        if (lane >= o) x += y;
    }
    if (lane == 63) wsum[wid] = x;
    __syncthreads();
    if (wid == 0 && lane < 8) {
        int wv = wsum[lane];
        #pragma unroll
        for (int o = 1; o < 8; o <<= 1) {
            int y = __shfl_up(wv, o);
            if (lane >= o) wv += y;
        }
        wsum[lane] = wv;
    }
    __syncthreads();
    int excl = ((wid > 0) ? wsum[wid - 1] : 0) + x - v;
    off[tid] = excl;
    cur[tid] = excl;
    if (v) gbase[tid] = atomicAdd(&bcur[tid], v);
    __syncthreads();
    #pragma unroll 4
    for (int k = 0; k < EPB / 512; ++k) {
        long e = e0 + tid + k * 512;
        if (e < E) {
            int dd = dst[e];
            int b = dd >> 8;
            int w = src[e] | ((dd & 255) << 17);
            int p = atomicAdd(&cur[b], 1);
            stage[p] = w;
        }
    }
    __syncthreads();
    // copy per-bucket runs to atomically-reserved global staging (coalesced bursts)
    for (int b = wid; b < nb; b += 8) {
        int c = cnt[b];
        int lo = off[b], go = gbase[b];
        for (int k = lane; k < c; k += 64) gstage[go + k] = stage[lo + k];
    }
}

// ---------------- phase 2: per-bucket rowptr + col scatter (single-writer) ----------
__global__ __launch_bounds__(256) void csr_scatter_kernel(const int* __restrict__ bucketptr,
                                                          const int* __restrict__ gstage,
                                                          int* __restrict__ rowptr,
                                                          int* __restrict__ col, int N, int nb) {
    __shared__ int cur[NPB];
    __shared__ int wsum[4];
    int tid = threadIdx.x, lane = tid & 63, wid = tid >> 6;
    int b = blockIdx.x;
    int node0 = b << 8;
    int ebase = bucketptr[b], eend = bucketptr[b + 1];
    cur[tid] = 0;
    __syncthreads();
    for (int e = ebase + tid; e < eend; e += 256)
        atomicAdd(&cur[((unsigned)gstage[e]) >> 17], 1);
    __syncthreads();
    int v = cur[tid];
    int x = v;
    #pragma unroll
    for (int o = 1; o < 64; o <<= 1) {
        int y = __shfl_up(x, o);
        if (lane >= o) x += y;
    }
    if (lane == 63) wsum[wid] = x;
    __syncthreads();
    if (tid == 0) {
        int a0 = wsum[0], a1 = wsum[1], a2 = wsum[2];
        wsum[0] = 0; wsum[1] = a0; wsum[2] = a0 + a1; wsum[3] = a0 + a1 + a2;
    }
    __syncthreads();
    int start = ebase + wsum[wid] + x - v;       // exclusive prefix = this node's CSR start
    if (node0 + tid < N) rowptr[node0 + tid] = start;
    cur[tid] = start;
    __syncthreads();
    for (int e = ebase + tid; e < eend; e += 256) {
        unsigned w = (unsigned)gstage[e];
        int p = atomicAdd(&cur[w >> 17], 1);
        col[p] = (int)(w & 0x1FFFFu);            // bucket col span ~17 KB: L2-resident, 1 writer
    }
    if (b == nb - 1 && tid == 0) rowptr[N] = eend;
}

// ---------------- GEMM1: h1 = relu(x @ W1 + b1), fused row L2-norm ----------------
// 256 rows/block, 256 threads, thread tile = 4 rows x 8 cols (32 FMA per ~5 LDS reads
// -> FMA-issue-bound, fixes round-2's LDS-read-bound 2x8 tile). Register prefetch
// pipeline keeps the once-per-chunk HBM wait behind a full compute phase.
__global__ __launch_bounds__(256) void gemm1_kernel(const float* __restrict__ x,
                                                    const float* __restrict__ W1,
                                                    const float* __restrict__ b1,
                                                    float* __restrict__ h1,
                                                    float* __restrict__ rn, int N) {
    __shared__ float xs[256][33];   // +1 pad, 33792 B
    __shared__ float w1s[32][32];   // 4096 B  -> 37888 B total, 4 blocks/CU
    int tid = threadIdx.x;
    int ct = tid & 3;               // col group: cols ct*8 .. ct*8+7
    int rt = tid >> 2;              // row group: rows rt*4 .. rt*4+3
    long row0 = (long)blockIdx.x * 256;

    float acc[4][8];
    #pragma unroll
    for (int q = 0; q < 4; ++q)
        #pragma unroll
        for (int j = 0; j < 8; ++j) acc[q][j] = 0.f;

    float4 xr[8];
    float w1r[4];

    // prefetch chunk 0  (256 rows x 32 k = 2048 float4s, 8 per thread)
    #pragma unroll
    for (int s = 0; s < 8; ++s) {
        int f4 = tid + (s << 8);
        int row = f4 >> 3;
        int c4 = (f4 & 7) << 2;
        long gr = row0 + row;
        xr[s] = make_float4(0.f, 0.f, 0.f, 0.f);
        if (gr < N) xr[s] = *(const float4*)(x + gr * F_IN + c4);
    }
    #pragma unroll
    for (int s = 0; s < 4; ++s) {
        int idx = tid + (s << 8);
        w1r[s] = W1[(long)(idx >> 5) * 32 + (idx & 31)];
    }

    for (int kc = 0; kc < 512; kc += 32) {
        __syncthreads();
        // commit prefetched chunk to LDS
        #pragma unroll
        for (int s = 0; s < 8; ++s) {
            int f4 = tid + (s << 8);
            int row = f4 >> 3;
            int c4 = (f4 & 7) << 2;
            xs[row][c4 + 0] = xr[s].x;
            xs[row][c4 + 1] = xr[s].y;
            xs[row][c4 + 2] = xr[s].z;
            xs[row][c4 + 3] = xr[s].w;
        }
        #pragma unroll
        for (int s = 0; s < 4; ++s) {
            int idx = tid + (s << 8);
            w1s[idx >> 5][idx & 31] = w1r[s];
        }
        __syncthreads();

        int kn = kc + 32;
        if (kn < 512) {
            #pragma unroll
            for (int s = 0; s < 8; ++s) {
                int f4 = tid + (s << 8);
                int row = f4 >> 3;
                int c4 = (f4 & 7) << 2;
                long gr = row0 + row;
                int k = kn + c4;
                xr[s] = make_float4(0.f, 0.f, 0.f, 0.f);
                if (gr < N && k < F_IN) xr[s] = *(const float4*)(x + gr * F_IN + k);
            }
            #pragma unroll
            for (int s = 0; s < 4; ++s) {
                int idx = tid + (s << 8);
                int kk = kn + (idx >> 5);
                w1r[s] = (kk < F_IN) ? W1[(long)kk * 32 + (idx & 31)] : 0.f;
            }
        }

        #pragma unroll 8
        for (int kk = 0; kk < 32; ++kk) {
            float4 wa = *(const float4*)&w1s[kk][ct * 8];
            float4 wb = *(const float4*)&w1s[kk][ct * 8 + 4];
            #pragma unroll
            for (int q = 0; q < 4; ++q) {
                float xv = xs[rt * 4 + q][kk];
                acc[q][0] += xv * wa.x; acc[q][1] += xv * wa.y;
                acc[q][2] += xv * wa.z; acc[q][3] += xv * wa.w;
                acc[q][4] += xv * wb.x; acc[q][5] += xv * wb.y;
                acc[q][6] += xv * wb.z; acc[q][7] += xv * wb.w;
            }
        }
    }

    float4 ba = *(const float4*)(b1 + ct * 8);
    float4 bb = *(const float4*)(b1 + ct * 8 + 4);
    #pragma unroll
    for (int q = 0; q < 4; ++q) {
        long gr = row0 + rt * 4 + q;
        float4 oa, ob;
        oa.x = fmaxf(acc[q][0] + ba.x, 0.f);
        oa.y = fmaxf(acc[q][1] + ba.y, 0.f);
        oa.z = fmaxf(acc[q][2] + ba.z, 0.f);
        oa.w = fmaxf(acc[q][3] + ba.w, 0.f);
        ob.x = fmaxf(acc[q][4] + bb.x, 0.f);
        ob.y = fmaxf(acc[q][5] + bb.y, 0.f);
        ob.z = fmaxf(acc[q][6] + bb.z, 0.f);
        ob.w = fmaxf(acc[q][7] + bb.w, 0.f);
        // fused row-norm: reduce sumsq across the 4 ct threads (consecutive lanes)
        float ss = oa.x * oa.x + oa.y * oa.y + oa.z * oa.z + oa.w * oa.w
                 + ob.x * ob.x + ob.y * ob.y + ob.z * ob.z + ob.w * ob.w;
        ss += __shfl_xor(ss, 1);
        ss += __shfl_xor(ss, 2);
        if (gr < N) {
            float* op = h1 + gr * 32 + ct * 8;
            *(float4*)op = oa;
            *(float4*)(op + 4) = ob;
            if (ct == 0) rn[gr] = rsqrtf(ss + 1e-12f);
        }
    }
}

// ---------------- fused AGNN conv: weights + aggregate in one pass ----------------
// 8 lanes per node; per edge: gather h[j] (float4/lane), dot via 3 shfl_xor,
// w = exp(beta*cos - |beta|) (softmax shift-invariance: logits in [-|b|,|b|]),
// accumulate s += w, acc += w*h[j]. Unroll 8 for deep independent gather chains
// (latency-bound kernel: more loads in flight per wave).
__global__ __launch_bounds__(256) void conv_kernel(const float* __restrict__ h,
                                                   const float* __restrict__ rn,
                                                   const int* __restrict__ rowptr,
                                                   const int* __restrict__ col,
                                                   const float* __restrict__ betaPtr,
                                                   float* __restrict__ out,
                                                   float* __restrict__ rnOut, int N) {
    int sub = threadIdx.x & 7;
    int i = blockIdx.x * 32 + (threadIdx.x >> 3);
    if (i >= N) return;
    float beta = betaPtr ? betaPtr[0] : 1.0f;
    float shift = fabsf(beta);
    long lsub = (long)(sub << 2);
    float4 hi = *(const float4*)(h + ((long)i << 5) + lsub);
    float bri = beta * rn[i];
    int e0 = rowptr[i];
    int e1 = rowptr[i + 1];

    float s = 0.f;
    float4 acc = make_float4(0.f, 0.f, 0.f, 0.f);
    int e = e0;
    for (; e + 8 <= e1; e += 8) {
        int jj[8];
        float rr[8], dd[8], ww[8];
        float4 vv[8];
        #pragma unroll
        for (int u = 0; u < 8; ++u) jj[u] = col[e + u];
        #pragma unroll
        for (int u = 0; u < 8; ++u) {
            rr[u] = rn[jj[u]];
            vv[u] = *(const float4*)(h + ((long)jj[u] << 5) + lsub);
        }
        #pragma unroll
        for (int u = 0; u < 8; ++u)
            dd[u] = hi.x * vv[u].x + hi.y * vv[u].y + hi.z * vv[u].z + hi.w * vv[u].w;
        #pragma unroll
        for (int u = 0; u < 8; ++u) dd[u] += __shfl_xor(dd[u], 1);
        #pragma unroll
        for (int u = 0; u < 8; ++u) dd[u] += __shfl_xor(dd[u], 2);
        #pragma unroll
        for (int u = 0; u < 8; ++u) dd[u] += __shfl_xor(dd[u], 4);
        #pragma unroll
        for (int u = 0; u < 8; ++u) ww[u] = __expf(bri * rr[u] * dd[u] - shift);
        #pragma unroll
        for (int u = 0; u < 8; ++u) {
            s += ww[u];
            acc.x += ww[u] * vv[u].x;
            acc.y += ww[u] * vv[u].y;
            acc.z += ww[u] * vv[u].z;
            acc.w += ww[u] * vv[u].w;
        }
    }
    for (; e + 4 <= e1; e += 4) {
        int j0 = col[e + 0], j1 = col[e + 1], j2 = col[e + 2], j3 = col[e + 3];
        float r0 = rn[j0], r1 = rn[j1], r2 = rn[j2], r3 = rn[j3];
        float4 v0 = *(const float4*)(h + ((long)j0 << 5) + lsub);
        float4 v1 = *(const float4*)(h + ((long)j1 << 5) + lsub);
        float4 v2 = *(const float4*)(h + ((long)j2 << 5) + lsub);
        float4 v3 = *(const float4*)(h + ((long)j3 << 5) + lsub);
        float d0 = hi.x * v0.x + hi.y * v0.y + hi.z * v0.z + hi.w * v0.w;
        float d1 = hi.x * v1.x + hi.y * v1.y + hi.z * v1.z + hi.w * v1.w;
        float d2 = hi.x * v2.x + hi.y * v2.y + hi.z * v2.z + hi.w * v2.w;
        float d3 = hi.x * v3.x + hi.y * v3.y + hi.z * v3.z + hi.w * v3.w;
        d0 += __shfl_xor(d0, 1); d1 += __shfl_xor(d1, 1);
        d2 += __shfl_xor(d2, 1); d3 += __shfl_xor(d3, 1);
        d0 += __shfl_xor(d0, 2); d1 += __shfl_xor(d1, 2);
        d2 += __shfl_xor(d2, 2); d3 += __shfl_xor(d3, 2);
        d0 += __shfl_xor(d0, 4); d1 += __shfl_xor(d1, 4);
        d2 += __shfl_xor(d2, 4); d3 += __shfl_xor(d3, 4);
        float w0 = __expf(bri * r0 * d0 - shift);
        float w1 = __expf(bri * r1 * d1 - shift);
        float w2 = __expf(bri * r2 * d2 - shift);
        float w3 = __expf(bri * r3 * d3 - shift);
        s += (w0 + w1) + (w2 + w3);
        acc.x += w0 * v0.x + w1 * v1.x + w2 * v2.x + w3 * v3.x;
        acc.y += w0 * v0.y + w1 * v1.y + w2 * v2.y + w3 * v3.y;
        acc.z += w0 * v0.z + w1 * v1.z + w2 * v2.z + w3 * v3.z;
        acc.w += w0 * v0.w + w1 * v1.w + w2 * v2.w + w3 * v3.w;
    }
    for (; e < e1; ++e) {
        int j = col[e];
        float rj = rn[j];
        float4 v = *(const float4*)(h + ((long)j << 5) + lsub);
        float d = hi.x * v.x + hi.y * v.y + hi.z * v.z + hi.w * v.w;
        d += __shfl_xor(d, 1);
        d += __shfl_xor(d, 2);
        d += __shfl_xor(d, 4);
        float w = __expf(bri * rj * d - shift);
        s += w;
        acc.x += w * v.x; acc.y += w * v.y; acc.z += w * v.z; acc.w += w * v.w;
    }

    float inv = 1.f / (s + 1e-16f);
    float4 o = make_float4(acc.x * inv, acc.y * inv, acc.z * inv, acc.w * inv);
    *(float4*)(out + ((long)i << 5) + lsub) = o;
    if (rnOut) {
        float ss = o.x * o.x + o.y * o.y + o.z * o.z + o.w * o.w;
        ss += __shfl_xor(ss, 1);
        ss += __shfl_xor(ss, 2);
        ss += __shfl_xor(ss, 4);
        if (sub == 0) rnOut[i] = rsqrtf(ss + 1e-12f);
    }
}

// ---------------- GEMM2: out = h3 @ W2 + b2, [N,32]@[32,40] ----------------
__global__ __launch_bounds__(256) void gemm2_kernel(const float* __restrict__ h3,
                                                    const float* __restrict__ W2,
                                                    const float* __restrict__ b2,
                                                    float* __restrict__ out, int N) {
    __shared__ float w2s[HID * NCLS];
    __shared__ float b2s[NCLS];
    for (int i = threadIdx.x; i < HID * NCLS; i += 256) w2s[i] = W2[i];
    if (threadIdx.x < NCLS) b2s[threadIdx.x] = b2[threadIdx.x];
    __syncthreads();

    int idx = blockIdx.x * 256 + threadIdx.x;
    if (idx >= N * NCLS) return;
    int n = idx / NCLS;
    int c = idx - n * NCLS;

    const float4* hp = (const float4*)(h3 + (long)n * 32);
    float acc = b2s[c];
    #pragma unroll
    for (int k4 = 0; k4 < 8; ++k4) {
        float4 hv = hp[k4];
        acc += hv.x * w2s[(k4 * 4 + 0) * NCLS + c];
        acc += hv.y * w2s[(k4 * 4 + 1) * NCLS + c];
        acc += hv.z * w2s[(k4 * 4 + 2) * NCLS + c];
        acc += hv.w * w2s[(k4 * 4 + 3) * NCLS + c];
    }
    out[idx] = acc;
}

// ---------------- launch ----------------

extern "C" void kernel_launch(void* const* d_in, const int* in_sizes, int n_in,
                              void* d_out, int out_size, void* d_ws, size_t ws_size,
                              hipStream_t stream) {
    const float* x     = (const float*)d_in[0];
    const float* W1    = (const float*)d_in[1];
    const float* b1    = (const float*)d_in[2];
    const float* W2    = (const float*)d_in[3];
    const float* b2    = (const float*)d_in[4];
    const float* beta2 = (const float*)d_in[5];
    const int*   ei    = (const int*)d_in[6];

    int N = in_sizes[0] / F_IN;        // 100000
    int E = in_sizes[6] / 2;           // 1700000
    const int* src = ei;
    const int* dst = ei + E;
    float* out = (float*)d_out;

    // workspace carve (256B aligned)
    char* p = (char*)d_ws;
    auto alloc = [&](size_t bytes) -> void* {
        void* r = (void*)p;
        p += (bytes + 255) & ~(size_t)255;
        return r;
    };
    float* h1  = (float*)alloc((size_t)N * 32 * 4);
    float* h2  = (float*)alloc((size_t)N * 32 * 4);
    float* rn1 = (float*)alloc((size_t)N * 4);
    float* rn2 = (float*)alloc((size_t)N * 4);
    int* rowptr    = (int*)alloc((size_t)(N + 1) * 4);
    int* col       = (int*)alloc((size_t)E * 4);
    int* gstage    = (int*)alloc((size_t)E * 4);
    int* gcnt      = (int*)alloc((size_t)MAXB * 4);
    int* bucketptr = (int*)alloc((size_t)(MAXB + 1) * 4);
    int* bcur      = (int*)alloc((size_t)MAXB * 4);
    float* h3 = h1;                    // conv2 output reuses h1 (free by then)

    int nb = (N + NPB - 1) / NPB;      // 391 buckets
    int p1blocks = (int)(((long)E + EPB - 1) / EPB);  // 104
    int cblocks = (N + 31) / 32;       // conv: 8 lanes/node

    gemm1_kernel<<<(N + 255) / 256, 256, 0, stream>>>(x, W1, b1, h1, rn1, N);

    // CSR build: count -> scan -> bin (staged, coalesced) -> per-bucket scatter
    hipMemsetAsync(gcnt, 0, (size_t)nb * 4, stream);
    csr_count_kernel<<<p1blocks, 256, 0, stream>>>(dst, E, gcnt, nb);
    csr_bscan_kernel<<<1, 512, 0, stream>>>(gcnt, bucketptr, bcur, nb);
    csr_bin_kernel<<<p1blocks, 512, 0, stream>>>(src, dst, E, bcur, gstage, nb);
    csr_scatter_kernel<<<nb, 256, 0, stream>>>(bucketptr, gstage, rowptr, col, N, nb);

    conv_kernel<<<cblocks, 256, 0, stream>>>(h1, rn1, rowptr, col, nullptr, h2, rn2, N);
    conv_kernel<<<cblocks, 256, 0, stream>>>(h2, rn2, rowptr, col, beta2, h3, nullptr, N);

    gemm2_kernel<<<(N * NCLS + 255) / 256, 256, 0, stream>>>(h3, W2, b2, out, N);
}